// Round 4
// baseline (380.170 us; speedup 1.0000x reference)
//
#include <hip/hip_runtime.h>
#include <hip/hip_bf16.h>
#include <math.h>

// Shapes (compile-time)
#define N_TOT 16384   // B*T
#define AG 8
#define OBSD 256
#define SD 512
#define NACT 32
#define ED 64
#define HYP 256

// ---------------- bf16 helpers / MFMA types ----------------
typedef __attribute__((ext_vector_type(8))) short bf16x8;   // 8 bf16 (4 VGPRs)
typedef __attribute__((ext_vector_type(4))) float f32x4;

__device__ __forceinline__ unsigned short f2bf(float f) {
    unsigned u = __float_as_uint(f);
    u += 0x7fffu + ((u >> 16) & 1u);          // round-to-nearest-even
    return (unsigned short)(u >> 16);
}
__device__ __forceinline__ float bf2f(unsigned short h) {
    return __uint_as_float(((unsigned)h) << 16);
}
#define MFMA16(a,b,c) __builtin_amdgcn_mfma_f32_16x16x32_bf16((a),(b),(c),0,0,0)
#define FRAG(p) (*(const bf16x8*)(p))

// ---------------- ws layout (bytes, 16B aligned) ----------------
#define WC_OFF     0u            // [192][264] bf16  (Wqkv @ Wobs folded)
#define WCAT_OFF   101376u       // [640][520] bf16 (Wh1a|Whfa|Wv1|Wb1)
#define WH1B_OFF   766976u       // [512][264] bf16
#define WHFB_OFF   1037312u      // [64][264] bf16
#define ACTTAB_OFF 1071104u      // [32][192] f32
#define WQEFF_OFF  1095680u      // [192] f32
#define BIASQ_OFF  1096448u      // [192] f32
#define WEFF_OFF   1097216u      // [64] f32
#define CATT_OFF   1097472u      // [1] f32 (+pad)
#define ATT_OFF    1097536u      // [16384*8] f32
#define WS_NEED    1621824u

// ===========================================================================
// Prep: weight conversion + algebraic folding (fp32 dots, then bf16 cast).
// ===========================================================================
__global__ __launch_bounds__(256) void k_prep(
    const float* __restrict__ W_obs, const float* __restrict__ W_act,
    const float* __restrict__ W_q,   const float* __restrict__ b_obs,
    const float* __restrict__ b_act, const float* __restrict__ b_q,
    const float* __restrict__ Wqkv,  const float* __restrict__ bqkv,
    const float* __restrict__ Wo,    const float* __restrict__ bo,
    const float* __restrict__ Wa2q,  const float* __restrict__ ba2q,
    const float* __restrict__ Wh1a, const float* __restrict__ Whfa,
    const float* __restrict__ Wv1,  const float* __restrict__ Wb1,
    const float* __restrict__ Wh1b, const float* __restrict__ Whfb,
    unsigned char* __restrict__ ws)
{
    unsigned short* wcat = (unsigned short*)(ws + WCAT_OFF);
    unsigned short* wh1b = (unsigned short*)(ws + WH1B_OFF);
    unsigned short* whfb = (unsigned short*)(ws + WHFB_OFF);
    unsigned short* wc   = (unsigned short*)(ws + WC_OFF);
    float* acttab = (float*)(ws + ACTTAB_OFF);
    float* wqeff  = (float*)(ws + WQEFF_OFF);
    float* biasq  = (float*)(ws + BIASQ_OFF);
    float* weff   = (float*)(ws + WEFF_OFF);
    float* catt   = (float*)(ws + CATT_OFF);

    const int TOT = 332800 + 135168 + 16896 + 49152 + 6144 + 192 + 192 + 64 + 1;
    for (int i = blockIdx.x * 256 + threadIdx.x; i < TOT; i += gridDim.x * 256) {
        int j = i;
        if (j < 332800) {                       // Wcat [640][520], K=512
            int r = j / 520, c = j - r * 520;
            float v = 0.f;
            if (c < 512) {
                if (r < 256)      v = Wh1a[r * 512 + c];
                else if (r < 512) v = Whfa[(r - 256) * 512 + c];
                else if (r < 576) v = Wv1[(r - 512) * 512 + c];
                else              v = Wb1[(r - 576) * 512 + c];
            }
            wcat[j] = f2bf(v);
        } else if ((j -= 332800) < 135168) {    // Wh1b [512][264], K=256
            int r = j / 264, c = j - r * 264;
            wh1b[j] = f2bf(c < 256 ? Wh1b[r * 256 + c] : 0.f);
        } else if ((j -= 135168) < 16896) {     // Whfb [64][264], K=256
            int r = j / 264, c = j - r * 264;
            whfb[j] = f2bf(c < 256 ? Whfb[r * 256 + c] : 0.f);
        } else if ((j -= 16896) < 49152) {      // Wc = Wqkv @ Wobs : [192][256]
            int r = j >> 8, c = j & 255;
            float s = 0.f;
            #pragma unroll 8
            for (int e = 0; e < 64; ++e) s += Wqkv[r * 64 + e] * W_obs[e * 256 + c];
            wc[r * 264 + c] = f2bf(s);
        } else if ((j -= 49152) < 6144) {       // acttab[act][r] = Wqkv @ W_act[:,act]
            int r = j >> 5, act = j & 31;
            float s = 0.f;
            #pragma unroll 8
            for (int e = 0; e < 64; ++e) s += Wqkv[r * 64 + e] * W_act[e * 32 + act];
            acttab[act * 192 + r] = s;
        } else if ((j -= 6144) < 192) {         // wqeff = Wqkv @ W_q[:,0]
            float s = 0.f;
            #pragma unroll 8
            for (int e = 0; e < 64; ++e) s += Wqkv[j * 64 + e] * W_q[e];
            wqeff[j] = s;
        } else if ((j -= 192) < 192) {          // biasq = Wqkv@(b_obs+b_act+b_q)+bqkv
            float s = bqkv[j];
            #pragma unroll 8
            for (int e = 0; e < 64; ++e)
                s += Wqkv[j * 64 + e] * (b_obs[e] + b_act[e] + b_q[e]);
            biasq[j] = s;
        } else if ((j -= 192) < 64) {           // weff[e] = sum_e' Wa2q[e']*Wo[e'][e]
            float s = 0.f;
            #pragma unroll 8
            for (int e2 = 0; e2 < 64; ++e2) s += Wa2q[e2] * Wo[e2 * 64 + j];
            weff[j] = s;
        } else {                                // catt = dot(bo,Wa2q)+ba2q
            float s = ba2q[0];
            #pragma unroll 8
            for (int e2 = 0; e2 < 64; ++e2) s += bo[e2] * Wa2q[e2];
            catt[0] = s;
        }
    }
}

// ===========================================================================
// K1: encoder+attention via folded Wc. 512 blocks x 8 tiles of 32 rows.
// Wc fragments in registers; register prefetch of next obs tile. (validated)
// ===========================================================================
#define TPB_TILES 8
__global__ __launch_bounds__(256, 2) void k_enc(
    const float* __restrict__ agent_qs,
    const float* __restrict__ observations,
    const int*   __restrict__ actions,
    const unsigned char* __restrict__ ws_w, float* __restrict__ attended)
{
    __shared__ __align__(16) unsigned short s_obs[32 * 264];
    __shared__ __align__(16) unsigned short s_qkv[32 * 200];
    __shared__ __align__(16) float s_att_tab[32 * 192];
    __shared__ __align__(16) float s_p[4][4][8][8];
    __shared__ float s_vw[4][8][4];
    __shared__ float s_weff[64], s_biasq[192], s_wqeff[192];
    __shared__ float s_qs[32], s_catt;
    __shared__ int   s_acts[32];

    const int t = threadIdx.x;
    const int w = t >> 6, lane = t & 63, m = lane & 15, q = lane >> 4;

    const unsigned short* wc = (const unsigned short*)(ws_w + WC_OFF);
    const float* acttab_g = (const float*)(ws_w + ACTTAB_OFF);
    const float* wqeff_g  = (const float*)(ws_w + WQEFF_OFF);
    const float* biasq_g  = (const float*)(ws_w + BIASQ_OFF);
    const float* weff_g   = (const float*)(ws_w + WEFF_OFF);
    const float* catt_g   = (const float*)(ws_w + CATT_OFF);

    for (int i = t; i < 1536; i += 256)
        ((float4*)s_att_tab)[i] = ((const float4*)acttab_g)[i];
    if (t < 192) { s_biasq[t] = biasq_g[t]; s_wqeff[t] = wqeff_g[t]; }
    if (t < 64)  s_weff[t] = weff_g[t];
    if (t == 0)  s_catt = catt_g[0];

    bf16x8 wf[3][8];
    #pragma unroll
    for (int ctl = 0; ctl < 3; ++ctl)
        #pragma unroll
        for (int kc = 0; kc < 8; ++kc)
            wf[ctl][kc] = FRAG(&wc[((w * 3 + ctl) * 16 + m) * 264 + kc * 32 + q * 8]);

    const int tb = blockIdx.x * TPB_TILES;
    const float4* obs4 = (const float4*)observations;

    float4 pf[8];
    {
        const int R0 = tb * 32;
        #pragma unroll
        for (int c = 0; c < 8; ++c) {
            int u = t + c * 256, row = u >> 6, x4 = u & 63;
            pf[c] = obs4[(size_t)(R0 + row) * 64 + x4];
        }
    }

    for (int it = 0; it < TPB_TILES; ++it) {
        const int R0 = (tb + it) * 32;
        #pragma unroll
        for (int c = 0; c < 8; ++c) {
            int u = t + c * 256, row = u >> 6, x4 = u & 63;
            float4 f = pf[c];
            ushort4 h = { f2bf(f.x), f2bf(f.y), f2bf(f.z), f2bf(f.w) };
            *(ushort4*)&s_obs[row * 264 + x4 * 4] = h;
        }
        if (t < 32) { s_acts[t] = actions[R0 + t]; s_qs[t] = agent_qs[R0 + t]; }
        __syncthreads();                       // B_a
        if (it + 1 < TPB_TILES) {
            const int R1 = (tb + it + 1) * 32;
            #pragma unroll
            for (int c = 0; c < 8; ++c) {
                int u = t + c * 256, row = u >> 6, x4 = u & 63;
                pf[c] = obs4[(size_t)(R1 + row) * 64 + x4];
            }
        }
        f32x4 acc[2][3];
        #pragma unroll
        for (int r2 = 0; r2 < 2; ++r2)
            #pragma unroll
            for (int c2 = 0; c2 < 3; ++c2) acc[r2][c2] = (f32x4){0.f,0.f,0.f,0.f};
        #pragma unroll
        for (int kc = 0; kc < 8; ++kc) {
            bf16x8 a0 = FRAG(&s_obs[(m)      * 264 + kc * 32 + q * 8]);
            bf16x8 a1 = FRAG(&s_obs[(16 + m) * 264 + kc * 32 + q * 8]);
            #pragma unroll
            for (int ctl = 0; ctl < 3; ++ctl) {
                acc[0][ctl] = MFMA16(a0, wf[ctl][kc], acc[0][ctl]);
                acc[1][ctl] = MFMA16(a1, wf[ctl][kc], acc[1][ctl]);
            }
        }
        #pragma unroll
        for (int rtl = 0; rtl < 2; ++rtl)
            #pragma unroll
            for (int ctl = 0; ctl < 3; ++ctl) {
                int j = (w * 3 + ctl) * 16 + m;
                #pragma unroll
                for (int r = 0; r < 4; ++r) {
                    int row = rtl * 16 + q * 4 + r;
                    float v = acc[rtl][ctl][r] + s_biasq[j]
                            + s_att_tab[s_acts[row] * 192 + j]
                            + s_qs[row] * s_wqeff[j];
                    s_qkv[row * 200 + j] = f2bf(v);
                }
            }
        __syncthreads();                       // B_b
        if (t < 128) {
            int n2 = t >> 5, h = (t >> 3) & 3, a = t & 7;
            int qrow = n2 * 8 + a;
            float qv[16];
            {
                bf16x8 qa = FRAG(&s_qkv[qrow * 200 + h * 16]);
                bf16x8 qb = FRAG(&s_qkv[qrow * 200 + h * 16 + 8]);
                #pragma unroll
                for (int d = 0; d < 8; ++d) {
                    qv[d]     = bf2f((unsigned short)qa[d]);
                    qv[d + 8] = bf2f((unsigned short)qb[d]);
                }
            }
            float sc[8], mx = -1e30f;
            #pragma unroll
            for (int b2 = 0; b2 < 8; ++b2) {
                bf16x8 ka = FRAG(&s_qkv[(n2 * 8 + b2) * 200 + 64 + h * 16]);
                bf16x8 kb = FRAG(&s_qkv[(n2 * 8 + b2) * 200 + 64 + h * 16 + 8]);
                float s = 0.f;
                #pragma unroll
                for (int d = 0; d < 8; ++d)
                    s += qv[d] * bf2f((unsigned short)ka[d])
                       + qv[d + 8] * bf2f((unsigned short)kb[d]);
                sc[b2] = s * 0.25f;
                mx = fmaxf(mx, sc[b2]);
            }
            float sum = 0.f;
            #pragma unroll
            for (int b2 = 0; b2 < 8; ++b2) { sc[b2] = __expf(sc[b2] - mx); sum += sc[b2]; }
            float inv = 1.f / sum;
            #pragma unroll
            for (int b2 = 0; b2 < 8; ++b2) s_p[n2][h][a][b2] = sc[b2] * inv;
        } else {
            int t2 = t - 128;
            int n2 = t2 >> 5, b2 = (t2 >> 2) & 7, h = t2 & 3;
            bf16x8 va = FRAG(&s_qkv[(n2 * 8 + b2) * 200 + 128 + h * 16]);
            bf16x8 vb = FRAG(&s_qkv[(n2 * 8 + b2) * 200 + 128 + h * 16 + 8]);
            float s = 0.f;
            #pragma unroll
            for (int d = 0; d < 8; ++d)
                s += bf2f((unsigned short)va[d]) * s_weff[h * 16 + d]
                   + bf2f((unsigned short)vb[d]) * s_weff[h * 16 + 8 + d];
            s_vw[n2][b2][h] = s;
        }
        __syncthreads();                       // B_c
        if (t < 32) {
            int n2 = t >> 3, a = t & 7;
            float s = s_catt;
            #pragma unroll
            for (int h = 0; h < 4; ++h)
                #pragma unroll
                for (int b2 = 0; b2 < 8; ++b2)
                    s += s_p[n2][h][a][b2] * s_vw[n2][b2][h];
            attended[R0 + t] = s;
        }
    }
}

// ===========================================================================
// K2 fused: hypernet layer-1 + layer-2 + mix, 64 rows per block, 512 threads.
// h1a/hfa/b1/vsum never leave LDS. Weight chunks register-prefetched.
// Layer-2 column-tiles arranged so hid accumulates in registers (no atomics).
// ===========================================================================
__global__ __launch_bounds__(512, 2) void k_hx(
    const float* __restrict__ states,
    const float* __restrict__ bh1a, const float* __restrict__ bhfa,
    const float* __restrict__ bv1,  const float* __restrict__ bb1,
    const float* __restrict__ Wv2,
    const float* __restrict__ bh1b, const float* __restrict__ bhfb,
    const float* __restrict__ bv2,
    const unsigned char* __restrict__ ws, float* __restrict__ out)
{
    __shared__ __align__(16) unsigned short s_st[64 * 520];   // 66.56 KB; later h1a|hfa [64][260]
    __shared__ __align__(16) unsigned short s_b[640 * 72];    // 92.16 KB; tail: b1 + vred

    const int t = threadIdx.x;
    const int w = t >> 6, lane = t & 63, m = lane & 15, q = lane >> 4;
    const int rt = w & 3, ch = w >> 2;
    const int n0 = blockIdx.x * 64;
    const int row0 = rt * 16 + q * 4;          // this thread's 4 D-rows

    const unsigned short* wcat = (const unsigned short*)(ws + WCAT_OFF);
    const unsigned short* wh1b = (const unsigned short*)(ws + WH1B_OFF);
    const unsigned short* whfb = (const unsigned short*)(ws + WHFB_OFF);
    const float* attended = (const float*)(ws + ATT_OFF);

    unsigned short* s_h1a = s_st;              // [64][260] bf16 (after L1)
    unsigned short* s_hfa = s_st + 64 * 260;   // [64][260] bf16
    unsigned short* s_b1  = s_b + 512 * 72;    // [64][68] bf16
    float* s_vred = (float*)(s_b + 512 * 72 + 64 * 68);  // [64][16] f32

    // ---- stage A: states fp32 -> bf16 [64][520] ----
    #pragma unroll
    for (int c = 0; c < 8; ++c) {
        int i = t + c * 512, row = i >> 6, x8 = i & 63;
        const float* sp = states + (size_t)(n0 + row) * 512 + x8 * 8;
        float4 f0 = *(const float4*)sp, f1 = *(const float4*)(sp + 4);
        bf16x8 h;
        h[0]=(short)f2bf(f0.x); h[1]=(short)f2bf(f0.y); h[2]=(short)f2bf(f0.z); h[3]=(short)f2bf(f0.w);
        h[4]=(short)f2bf(f1.x); h[5]=(short)f2bf(f1.y); h[6]=(short)f2bf(f1.z); h[7]=(short)f2bf(f1.w);
        *(bf16x8*)&s_st[row * 520 + x8 * 8] = h;
    }

    // ---- Layer 1: [64][512] @ Wcat^T -> 640 outs; K chunks of 64, prefetched ----
    uint4 pf[10];
    #pragma unroll
    for (int c = 0; c < 10; ++c) {
        int i = t + c * 512, jl = i >> 3, x8 = i & 7;
        pf[c] = *(const uint4*)&wcat[(size_t)jl * 520 + x8 * 8];
    }
    f32x4 acc[20];
    #pragma unroll
    for (int i = 0; i < 20; ++i) acc[i] = (f32x4){0.f,0.f,0.f,0.f};

    for (int s = 0; s < 8; ++s) {
        #pragma unroll
        for (int c = 0; c < 10; ++c) {
            int i = t + c * 512, jl = i >> 3, x8 = i & 7;
            *(uint4*)&s_b[jl * 72 + x8 * 8] = pf[c];
        }
        __syncthreads();                       // staged chunk (and, iter 0, s_st) visible
        if (s + 1 < 8) {
            #pragma unroll
            for (int c = 0; c < 10; ++c) {
                int i = t + c * 512, jl = i >> 3, x8 = i & 7;
                pf[c] = *(const uint4*)&wcat[(size_t)jl * 520 + (s + 1) * 64 + x8 * 8];
            }
        }
        #pragma unroll
        for (int kc2 = 0; kc2 < 2; ++kc2) {
            bf16x8 a = FRAG(&s_st[(rt * 16 + m) * 520 + s * 64 + kc2 * 32 + q * 8]);
            #pragma unroll
            for (int ctl = 0; ctl < 20; ++ctl) {
                bf16x8 b = FRAG(&s_b[((ch * 20 + ctl) * 16 + m) * 72 + kc2 * 32 + q * 8]);
                acc[ctl] = MFMA16(a, b, acc[ctl]);
            }
        }
        __syncthreads();                       // MFMAs done before restage / epilogue
    }

    // ---- L1 epilogue: h1a/hfa -> LDS (states region dead), b1 + vred -> s_b tail ----
    {
        float vp[4] = {0.f, 0.f, 0.f, 0.f};
        #pragma unroll
        for (int ctl = 0; ctl < 20; ++ctl) {
            int ct = ch * 20 + ctl, jj = ct * 16 + m;
            if (ct < 16) {
                float bb = bh1a[jj];
                #pragma unroll
                for (int r = 0; r < 4; ++r)
                    s_h1a[(row0 + r) * 260 + jj] = f2bf(fmaxf(acc[ctl][r] + bb, 0.f));
            } else if (ct < 32) {
                float bb = bhfa[jj - 256];
                #pragma unroll
                for (int r = 0; r < 4; ++r)
                    s_hfa[(row0 + r) * 260 + (jj - 256)] = f2bf(fmaxf(acc[ctl][r] + bb, 0.f));
            } else if (ct < 36) {
                float bb = bv1[jj - 512], wv = Wv2[jj - 512];
                #pragma unroll
                for (int r = 0; r < 4; ++r) vp[r] += fmaxf(acc[ctl][r] + bb, 0.f) * wv;
            } else {
                float bb = bb1[jj - 576];
                #pragma unroll
                for (int r = 0; r < 4; ++r)
                    s_b1[(row0 + r) * 68 + (jj - 576)] = f2bf(acc[ctl][r] + bb);
            }
        }
        if (ch == 1) {
            #pragma unroll
            for (int r = 0; r < 4; ++r) s_vred[(row0 + r) * 16 + m] = vp[r];
        }
    }

    // aq values for this thread's rows (L2-hot, 8 floats/row)
    float aqv[8][4];
    #pragma unroll
    for (int r = 0; r < 4; ++r) {
        const float* ap = attended + (size_t)(n0 + row0 + r) * 8;
        float4 a0 = *(const float4*)ap, a1 = *(const float4*)(ap + 4);
        aqv[0][r]=a0.x; aqv[1][r]=a0.y; aqv[2][r]=a0.z; aqv[3][r]=a0.w;
        aqv[4][r]=a1.x; aqv[5][r]=a1.y; aqv[6][r]=a1.z; aqv[7][r]=a1.w;
    }

    // ---- Layer 2a: w1 = h1a @ Wh1b^T; wave (ch) owns eq {2ch,2ch+1} for ALL a ----
    uint4 pf2[8];
    #pragma unroll
    for (int c = 0; c < 8; ++c) {
        int i = t + c * 512, jl = i >> 3, x8 = i & 7;
        pf2[c] = *(const uint4*)&wh1b[(size_t)jl * 264 + x8 * 8];
    }
    f32x4 acc2[16];
    #pragma unroll
    for (int i = 0; i < 16; ++i) acc2[i] = (f32x4){0.f,0.f,0.f,0.f};

    for (int s = 0; s < 4; ++s) {
        #pragma unroll
        for (int c = 0; c < 8; ++c) {
            int i = t + c * 512, jl = i >> 3, x8 = i & 7;
            *(uint4*)&s_b[jl * 72 + x8 * 8] = pf2[c];
        }
        __syncthreads();                       // staged chunk + (iter 0) L1 epilogue visible
        if (s + 1 < 4) {
            #pragma unroll
            for (int c = 0; c < 8; ++c) {
                int i = t + c * 512, jl = i >> 3, x8 = i & 7;
                pf2[c] = *(const uint4*)&wh1b[(size_t)jl * 264 + (s + 1) * 64 + x8 * 8];
            }
        }
        #pragma unroll
        for (int kc2 = 0; kc2 < 2; ++kc2) {
            bf16x8 a = FRAG(&s_h1a[(rt * 16 + m) * 260 + s * 64 + kc2 * 32 + q * 8]);
            #pragma unroll
            for (int ctl = 0; ctl < 16; ++ctl) {
                int jrow = (ctl >> 1) * 64 + (ch * 2 + (ctl & 1)) * 16;
                bf16x8 b = FRAG(&s_b[(jrow + m) * 72 + kc2 * 32 + q * 8]);
                acc2[ctl] = MFMA16(a, b, acc2[ctl]);
            }
        }
        __syncthreads();
    }

    // hid accumulation (registers, no atomics)
    f32x4 hid[2] = { {0.f,0.f,0.f,0.f}, {0.f,0.f,0.f,0.f} };
    #pragma unroll
    for (int ctl = 0; ctl < 16; ++ctl) {
        int a2 = ctl >> 1, eql = ctl & 1;
        int jj = a2 * 64 + (ch * 2 + eql) * 16 + m;
        float bb = bh1b[jj];
        #pragma unroll
        for (int r = 0; r < 4; ++r)
            hid[eql][r] += aqv[a2][r] * fabsf(acc2[ctl][r] + bb);
    }

    // ---- Layer 2b: w_f = |hfa @ Whfb^T + b|; elu; product-sum ----
    bf16x8 wb[2][8];
    #pragma unroll
    for (int eql = 0; eql < 2; ++eql)
        #pragma unroll
        for (int kc = 0; kc < 8; ++kc)
            wb[eql][kc] = FRAG(&whfb[((ch * 2 + eql) * 16 + m) * 264 + kc * 32 + q * 8]);
    f32x4 wfacc[2] = { {0.f,0.f,0.f,0.f}, {0.f,0.f,0.f,0.f} };
    #pragma unroll
    for (int kc = 0; kc < 8; ++kc) {
        bf16x8 a = FRAG(&s_hfa[(rt * 16 + m) * 260 + kc * 32 + q * 8]);
        #pragma unroll
        for (int eql = 0; eql < 2; ++eql) wfacc[eql] = MFMA16(a, wb[eql][kc], wfacc[eql]);
    }
    float prt[4] = {0.f, 0.f, 0.f, 0.f};
    #pragma unroll
    for (int eql = 0; eql < 2; ++eql) {
        int e = (ch * 2 + eql) * 16 + m;
        float bb = bhfb[e];
        #pragma unroll
        for (int r = 0; r < 4; ++r) {
            float wfv = fabsf(wfacc[eql][r] + bb);
            float hv = hid[eql][r] + bf2f(s_b1[(row0 + r) * 68 + e]);
            hv = (hv > 0.f) ? hv : expm1f(hv);
            prt[r] += wfv * hv;
        }
    }
    __syncthreads();                           // h1a region dead -> reuse as s_red
    float* s_red = (float*)s_h1a;              // [64][32] f32
    #pragma unroll
    for (int r = 0; r < 4; ++r)
        s_red[(row0 + r) * 32 + ch * 16 + m] = prt[r];
    __syncthreads();
    if (t < 64) {
        float y = bv2[0];
        #pragma unroll
        for (int mm = 0; mm < 16; ++mm) y += s_vred[t * 16 + mm];
        #pragma unroll
        for (int i = 0; i < 32; ++i) y += s_red[t * 32 + i];
        out[n0 + t] = y;
    }
}

// ===========================================================================
// Fallback (round-1, validated) kernels — used if ws_size is too small.
// ===========================================================================
#define NBF 16
__global__ __launch_bounds__(256) void k_enc_attn_fb(
    const float* __restrict__ agent_qs, const float* __restrict__ observations,
    const int* __restrict__ actions,
    const float* __restrict__ W_obs, const float* __restrict__ b_obs,
    const float* __restrict__ W_act, const float* __restrict__ b_act,
    const float* __restrict__ W_q,   const float* __restrict__ b_q,
    const float* __restrict__ Wqkv,  const float* __restrict__ bqkv,
    const float* __restrict__ Wo,    const float* __restrict__ bo,
    const float* __restrict__ Wa2q,  const float* __restrict__ ba2q,
    float* __restrict__ attended)
{
    __shared__ __align__(16) float s_obs[AG][OBSD];
    __shared__ __align__(16) float s_x[AG][ED];
    __shared__ __align__(16) float s_qkv[AG][3*ED];
    __shared__ float s_p[4][AG][AG];
    __shared__ __align__(16) float s_o[AG][ED];
    const int n = blockIdx.x, t = threadIdx.x;
    { const float4* g = (const float4*)(observations + (size_t)n*(AG*OBSD));
      float4* s4 = (float4*)&s_obs[0][0];
      for (int i = 0; i < 2; ++i) s4[t + i*256] = g[t + i*256]; }
    __syncthreads();
    { const int e = t & 63, a0 = t >> 6;
      const float wq = W_q[e]; const float bias0 = b_obs[e]+b_act[e]+b_q[e];
      const float* wrow = W_obs + e*OBSD;
      for (int g = 0; g < 2; ++g) { const int a = a0 + g*4; float acc = 0.f;
        for (int k = 0; k < OBSD; k += 4) { const float4 wv = *(const float4*)(wrow+k);
          acc += wv.x*s_obs[a][k]+wv.y*s_obs[a][k+1]+wv.z*s_obs[a][k+2]+wv.w*s_obs[a][k+3]; }
        s_x[a][e] = acc + bias0 + W_act[e*NACT + actions[n*AG+a]] + agent_qs[n*AG+a]*wq; } }
    __syncthreads();
    for (int g = 0; g < 6; ++g) { const int i = t + g*256, a = i/192, j = i - a*192;
      const float* wrow = Wqkv + j*ED; float acc = bqkv[j];
      for (int k = 0; k < ED; k += 4) { const float4 wv = *(const float4*)(wrow+k);
        acc += wv.x*s_x[a][k]+wv.y*s_x[a][k+1]+wv.z*s_x[a][k+2]+wv.w*s_x[a][k+3]; }
      s_qkv[a][j] = acc; }
    __syncthreads();
    { const int h = t>>6, a = (t>>3)&7, b = t&7; float acc = 0.f;
      for (int d = 0; d < 16; ++d) acc += s_qkv[a][h*16+d]*s_qkv[b][64+h*16+d];
      s_p[h][a][b] = acc*0.25f; }
    __syncthreads();
    if (t < 32) { const int h = t>>3, a = t&7; float mm = -1e30f;
      for (int b = 0; b < 8; ++b) mm = fmaxf(mm, s_p[h][a][b]);
      float ex[8], sum = 0.f;
      for (int b = 0; b < 8; ++b) { ex[b] = __expf(s_p[h][a][b]-mm); sum += ex[b]; }
      for (int b = 0; b < 8; ++b) s_p[h][a][b] = ex[b]/sum; }
    __syncthreads();
    for (int g = 0; g < 2; ++g) { const int i = t+g*256, a = i>>6, c = i&63, h = c>>4;
      float acc = 0.f;
      for (int b = 0; b < 8; ++b) acc += s_p[h][a][b]*s_qkv[b][128+c];
      s_o[a][c] = acc; }
    __syncthreads();
    for (int g = 0; g < 2; ++g) { const int i = t+g*256, a = i>>6, e2 = i&63;
      const float* wrow = Wo + e2*ED; float acc = bo[e2];
      for (int k = 0; k < ED; k += 4) { const float4 wv = *(const float4*)(wrow+k);
        acc += wv.x*s_o[a][k]+wv.y*s_o[a][k+1]+wv.z*s_o[a][k+2]+wv.w*s_o[a][k+3]; }
      s_x[a][e2] = acc * Wa2q[e2]; }
    __syncthreads();
    if (t < 8) { float s = ba2q[0];
      for (int e2 = 0; e2 < 64; ++e2) s += s_x[t][e2];
      attended[n*AG+t] = s; }
}

__global__ __launch_bounds__(256) void k_mixer_fb(
    const float* __restrict__ states, const float* __restrict__ attended,
    const float* __restrict__ Wh1a, const float* __restrict__ bh1a,
    const float* __restrict__ Wh1b, const float* __restrict__ bh1b,
    const float* __restrict__ Whfa, const float* __restrict__ bhfa,
    const float* __restrict__ Whfb, const float* __restrict__ bhfb,
    const float* __restrict__ Wb1,  const float* __restrict__ bb1,
    const float* __restrict__ Wv1,  const float* __restrict__ bv1,
    const float* __restrict__ Wv2,  const float* __restrict__ bv2,
    float* __restrict__ out)
{
    __shared__ __align__(16) float s_st[NBF][SD];
    __shared__ __align__(16) float s_h[NBF][HYP];
    __shared__ __align__(16) float s_hid[NBF][ED];
    __shared__ __align__(16) float s_prod[NBF][ED];
    __shared__ __align__(16) float s_v[NBF][ED];
    __shared__ float s_aq[NBF][AG];
    const int n0 = blockIdx.x * NBF, t = threadIdx.x;
    { const float4* g = (const float4*)(states + (size_t)n0*SD);
      float4* s4 = (float4*)&s_st[0][0];
      for (int i = 0; i < 8; ++i) s4[t + i*256] = g[t + i*256];
      if (t < NBF*AG) ((float*)s_aq)[t] = attended[n0*AG + t]; }
    __syncthreads();
    { const float* wrow = Wh1a + t*SD; float acc[NBF];
      for (int n = 0; n < NBF; ++n) acc[n] = 0.f;
      for (int k = 0; k < SD; k += 4) { const float4 wv = *(const float4*)(wrow+k);
        for (int n = 0; n < NBF; ++n) { const float4 x = *(const float4*)(&s_st[n][k]);
          acc[n] += wv.x*x.x+wv.y*x.y+wv.z*x.z+wv.w*x.w; } }
      const float bb = bh1a[t];
      for (int n = 0; n < NBF; ++n) s_h[n][t] = fmaxf(acc[n]+bb, 0.f); }
    for (int g = 0; g < 4; ++g) { const int i = t+g*256, n = i>>6, e = i&63;
      const float* wrow = Wb1 + e*SD; float acc = bb1[e];
      for (int k = 0; k < SD; k += 4) { const float4 wv = *(const float4*)(wrow+k);
        const float4 x = *(const float4*)(&s_st[n][k]);
        acc += wv.x*x.x+wv.y*x.y+wv.z*x.z+wv.w*x.w; }
      s_hid[n][e] = acc; }
    __syncthreads();
    for (int g = 0; g < 2; ++g) { const int j = t+g*256;
      const float* wrow = Wh1b + j*HYP; float acc[NBF];
      for (int n = 0; n < NBF; ++n) acc[n] = 0.f;
      for (int k = 0; k < HYP; k += 4) { const float4 wv = *(const float4*)(wrow+k);
        for (int n = 0; n < NBF; ++n) { const float4 x = *(const float4*)(&s_h[n][k]);
          acc[n] += wv.x*x.x+wv.y*x.y+wv.z*x.z+wv.w*x.w; } }
      const float bb = bh1b[j]; const int a = j>>6, e = j&63;
      for (int n = 0; n < NBF; ++n)
        atomicAdd(&s_hid[n][e], s_aq[n][a]*fabsf(acc[n]+bb)); }
    __syncthreads();
    { const float* wrow = Whfa + t*SD; float acc[NBF];
      for (int n = 0; n < NBF; ++n) acc[n] = 0.f;
      for (int k = 0; k < SD; k += 4) { const float4 wv = *(const float4*)(wrow+k);
        for (int n = 0; n < NBF; ++n) { const float4 x = *(const float4*)(&s_st[n][k]);
          acc[n] += wv.x*x.x+wv.y*x.y+wv.z*x.z+wv.w*x.w; } }
      const float bb = bhfa[t];
      for (int n = 0; n < NBF; ++n) s_h[n][t] = fmaxf(acc[n]+bb, 0.f); }
    __syncthreads();
    for (int g = 0; g < 4; ++g) { const int i = t+g*256, n = i>>6, e = i&63;
      { const float* wrow = Whfb + e*HYP; float acc = bhfb[e];
        for (int k = 0; k < HYP; k += 4) { const float4 wv = *(const float4*)(wrow+k);
          const float4 x = *(const float4*)(&s_h[n][k]);
          acc += wv.x*x.x+wv.y*x.y+wv.z*x.z+wv.w*x.w; }
        float h = s_hid[n][e]; h = (h > 0.f) ? h : expm1f(h);
        s_prod[n][e] = fabsf(acc)*h; }
      { const float* wrow = Wv1 + e*SD; float acc = bv1[e];
        for (int k = 0; k < SD; k += 4) { const float4 wv = *(const float4*)(wrow+k);
          const float4 x = *(const float4*)(&s_st[n][k]);
          acc += wv.x*x.x+wv.y*x.y+wv.z*x.z+wv.w*x.w; }
        s_v[n][e] = fmaxf(acc, 0.f)*Wv2[e]; } }
    __syncthreads();
    if (t < NBF) { float y = bv2[0];
      for (int e = 0; e < ED; ++e) y += s_prod[t][e] + s_v[t][e];
      out[n0+t] = y; }
}

// ===========================================================================
extern "C" void kernel_launch(void* const* d_in, const int* in_sizes, int n_in,
                              void* d_out, int out_size, void* d_ws, size_t ws_size,
                              hipStream_t stream) {
    const float* agent_qs     = (const float*)d_in[0];
    const float* states       = (const float*)d_in[1];
    const float* observations = (const float*)d_in[2];
    const int*   actions      = (const int*)  d_in[3];
    const float* W_obs = (const float*)d_in[4];  const float* b_obs = (const float*)d_in[5];
    const float* W_act = (const float*)d_in[6];  const float* b_act = (const float*)d_in[7];
    const float* W_q   = (const float*)d_in[8];  const float* b_q   = (const float*)d_in[9];
    const float* Wqkv  = (const float*)d_in[10]; const float* bqkv  = (const float*)d_in[11];
    const float* Wo    = (const float*)d_in[12]; const float* bo    = (const float*)d_in[13];
    const float* Wa2q  = (const float*)d_in[14]; const float* ba2q  = (const float*)d_in[15];
    const float* Wh1a  = (const float*)d_in[16]; const float* bh1a  = (const float*)d_in[17];
    const float* Wh1b  = (const float*)d_in[18]; const float* bh1b  = (const float*)d_in[19];
    const float* Whfa  = (const float*)d_in[20]; const float* bhfa  = (const float*)d_in[21];
    const float* Whfb  = (const float*)d_in[22]; const float* bhfb  = (const float*)d_in[23];
    const float* Wb1   = (const float*)d_in[24]; const float* bb1   = (const float*)d_in[25];
    const float* Wv1   = (const float*)d_in[26]; const float* bv1   = (const float*)d_in[27];
    const float* Wv2   = (const float*)d_in[28]; const float* bv2   = (const float*)d_in[29];
    float* out = (float*)d_out;

    if (ws_size >= WS_NEED) {
        unsigned char* ws = (unsigned char*)d_ws;
        float* attended = (float*)(ws + ATT_OFF);
        k_prep<<<512, 256, 0, stream>>>(W_obs, W_act, W_q, b_obs, b_act, b_q,
                                        Wqkv, bqkv, Wo, bo, Wa2q, ba2q,
                                        Wh1a, Whfa, Wv1, Wb1, Wh1b, Whfb, ws);
        k_enc<<<512, 256, 0, stream>>>(agent_qs, observations, actions, ws, attended);
        k_hx<<<N_TOT / 64, 512, 0, stream>>>(states, bh1a, bhfa, bv1, bb1, Wv2,
                                             bh1b, bhfb, bv2, ws, out);
    } else {
        float* attended = (float*)d_ws;
        k_enc_attn_fb<<<N_TOT, 256, 0, stream>>>(agent_qs, observations, actions,
            W_obs, b_obs, W_act, b_act, W_q, b_q, Wqkv, bqkv, Wo, bo, Wa2q, ba2q, attended);
        k_mixer_fb<<<N_TOT / NBF, 256, 0, stream>>>(states, attended,
            Wh1a, bh1a, Wh1b, bh1b, Whfa, bhfa, Whfb, bhfb,
            Wb1, bb1, Wv1, bv1, Wv2, bv2, out);
    }
}